// Round 3
// baseline (2198.505 us; speedup 1.0000x reference)
//
#include <hip/hip_runtime.h>

// Router_15942918603252 — MI355X implementation (R3).
// R3 change: all GEMM epilogues go through a wave-private LDS strip and issue
// 16 B/lane coalesced global stores (full 64 B lines). R2's scalar 2 B stores
// produced 32 B partial-line segments -> L2 write-allocate RMW (~100 MB extra
// FETCH on G1, similar on expert) + long scalar store tails.
//
// Pipeline: prep (split/transpose) -> G1 orig = x@W_in+b_in (3-pass split
// fp16) -> G2 PQ = orig@[diag(Wc)Wr1|diag(bc)Wr1] -> 4x { router softmax;
// per-expert weighted partial GEMMs (grid.z=m); combine8 } -> G3 out.
// max_cycles==4 hardcoded (setup constant). lo = (v - fp16(v))*2048.

typedef _Float16 half8 __attribute__((ext_vector_type(8)));
typedef _Float16 half4v __attribute__((ext_vector_type(4)));
typedef float floatx4 __attribute__((ext_vector_type(4)));

#define DEVI __device__ __forceinline__
#define LO_SCALE 2048.0f
#define LO_INV (1.0f / 2048.0f)
// LDS strip strides (elements): chosen so rows 4 apart differ by 16 banks and
// rows 8 apart alias 2-way (free, m136), while keeping 16 B alignment.
#define H_STRIDE 72  // fp16 strip: 72*2=144 B/row
#define F_STRIDE 68  // f32  strip: 68*4=272 B/row

DEVI void async16(void* lds, const void* g) {
  __builtin_amdgcn_global_load_lds(
      (const __attribute__((address_space(1))) unsigned int*)g,
      (__attribute__((address_space(3))) unsigned int*)lds, 16, 0, 0);
}

DEVI floatx4 mfma_f16(half8 a, half8 b, floatx4 c) {
  return __builtin_amdgcn_mfma_f32_16x16x32_f16(a, b, c, 0, 0, 0);
}

// ---------------- prep kernels ----------------

__global__ __launch_bounds__(256) void k_split(const float* __restrict__ in,
                                               _Float16* __restrict__ hi,
                                               _Float16* __restrict__ lo,
                                               int n4) {
  int i = blockIdx.x * 256 + threadIdx.x;
  if (i >= n4) return;
  float4 v = ((const float4*)in)[i];
  float vv[4] = {v.x, v.y, v.z, v.w};
  half4v h, l;
#pragma unroll
  for (int k = 0; k < 4; k++) {
    _Float16 hh = (_Float16)vv[k];
    h[k] = hh;
    l[k] = (_Float16)((vv[k] - (float)hh) * LO_SCALE);
  }
  ((half4v*)hi)[i] = h;
  ((half4v*)lo)[i] = l;
}

// in: [batch][R][C] f32; optional per-input-row scale[r].
// out_hi/out_lo: [batch][C][R] fp16 (transposed, k-contiguous)
__global__ __launch_bounds__(256) void k_transpose_split(
    const float* __restrict__ in, const float* __restrict__ scale,
    _Float16* __restrict__ oh, _Float16* __restrict__ ol, int R, int C) {
  __shared__ float tile[64][65];
  __shared__ float srow[64];
  int b = blockIdx.z;
  int r0 = blockIdx.y * 64, c0 = blockIdx.x * 64;
  const float* src = in + (size_t)b * R * C;
  int t = threadIdx.x;
  int lr = t >> 4;
  int lc4 = (t & 15) * 4;
#pragma unroll
  for (int rr = 0; rr < 64; rr += 16) {
    float4 v = *(const float4*)&src[(size_t)(r0 + lr + rr) * C + c0 + lc4];
    tile[lr + rr][lc4 + 0] = v.x;
    tile[lr + rr][lc4 + 1] = v.y;
    tile[lr + rr][lc4 + 2] = v.z;
    tile[lr + rr][lc4 + 3] = v.w;
  }
  if (t < 64) srow[t] = scale ? scale[r0 + t] : 1.0f;
  __syncthreads();
  int oc = t >> 2;
  int orr = (t & 3) * 16;
  alignas(16) _Float16 hv[16];
  alignas(16) _Float16 lv[16];
#pragma unroll
  for (int k = 0; k < 16; k++) {
    float v = tile[orr + k][oc] * srow[orr + k];
    _Float16 h = (_Float16)v;
    hv[k] = h;
    lv[k] = (_Float16)((v - (float)h) * LO_SCALE);
  }
  size_t ob = (size_t)b * C * R + (size_t)(c0 + oc) * R + (r0 + orr);
  ((int4*)&oh[ob])[0] = ((int4*)hv)[0];
  ((int4*)&oh[ob])[1] = ((int4*)hv)[1];
  if (ol) {
    ((int4*)&ol[ob])[0] = ((int4*)lv)[0];
    ((int4*)&ol[ob])[1] = ((int4*)lv)[1];
  }
}

// ---- epilogue helpers: wave-private LDS bounce, coalesced 16 B stores ----

// Flush one 16x64 fp16 block (i fixed): vals[j][r] indexed by MFMA C-layout
// (row=(lane>>4)*4+r, col=j*16+(lane&15)); writes rows gr0..gr0+15 at gcol0.
DEVI void flush16x64_f16(_Float16* strip, const float* vals, int lane,
                         _Float16* __restrict__ out, size_t gr0, int gcol0,
                         int N) {
  int r0 = (lane >> 4) * 2;  // vals laid as [j][r]: r index below
#pragma unroll
  for (int j = 0; j < 4; j++)
#pragma unroll
    for (int r = 0; r < 4; r++)
      strip[((lane >> 4) * 4 + r) * H_STRIDE + j * 16 + (lane & 15)] =
          (_Float16)vals[j * 4 + r];
  (void)r0;
#pragma unroll
  for (int p = 0; p < 2; p++) {
    half8 v = *(half8*)&strip[(p * 8 + (lane >> 3)) * H_STRIDE + (lane & 7) * 8];
    *(half8*)&out[(gr0 + p * 8 + (lane >> 3)) * (size_t)N + gcol0 +
                  (lane & 7) * 8] = v;
  }
}

// Same for f32 output.
DEVI void flush16x64_f32(float* strip, const float* vals, int lane,
                         float* __restrict__ out, size_t gr0, int gcol0,
                         int N) {
#pragma unroll
  for (int j = 0; j < 4; j++)
#pragma unroll
    for (int r = 0; r < 4; r++)
      strip[((lane >> 4) * 4 + r) * F_STRIDE + j * 16 + (lane & 15)] =
          vals[j * 4 + r];
#pragma unroll
  for (int p = 0; p < 4; p++) {
    float4 v =
        *(float4*)&strip[(p * 4 + (lane >> 4)) * F_STRIDE + (lane & 15) * 4];
    *(float4*)&out[(gr0 + p * 4 + (lane >> 4)) * (size_t)N + gcol0 +
                   (lane & 15) * 4] = v;
  }
}

// ---------------- GEMM kernels (m97 structure: 128x128 tile, 4 waves) -------

// 3-pass split GEMM, writes split fp16 outputs (G1)
__global__ __launch_bounds__(256) void k_gemm3_split(
    const _Float16* __restrict__ Ah, const _Float16* __restrict__ Al,
    const _Float16* __restrict__ Bh, const _Float16* __restrict__ Bl,
    const float* __restrict__ bias, _Float16* __restrict__ Ohi,
    _Float16* __restrict__ Olo, int M, int N, int K) {
  __shared__ _Float16 sAh[128 * 32], sAl[128 * 32], sBh[128 * 32],
      sBl[128 * 32];
  __shared__ _Float16 sC[4 * 16 * H_STRIDE];
  int t = threadIdx.x, lane = t & 63, wave = t >> 6;
  int wr = wave >> 1, wc = wave & 1;
  int row0 = blockIdx.y * 128, col0 = blockIdx.x * 128;
  floatx4 acc[4][4], ac2[4][4];
  for (int i = 0; i < 4; i++)
    for (int j = 0; j < 4; j++) {
      acc[i][j] = (floatx4){0.f, 0.f, 0.f, 0.f};
      ac2[i][j] = (floatx4){0.f, 0.f, 0.f, 0.f};
    }
  int rr0 = t >> 2, kk0 = (t & 3) * 8;
  int ar = (lane & 15) * 32 + (lane >> 4) * 8;
  for (int k0 = 0; k0 < K; k0 += 32) {
    __syncthreads();
    async16(&sAh[t * 8], &Ah[(size_t)(row0 + rr0) * K + k0 + kk0]);
    async16(&sAh[(t + 256) * 8], &Ah[(size_t)(row0 + rr0 + 64) * K + k0 + kk0]);
    async16(&sAl[t * 8], &Al[(size_t)(row0 + rr0) * K + k0 + kk0]);
    async16(&sAl[(t + 256) * 8], &Al[(size_t)(row0 + rr0 + 64) * K + k0 + kk0]);
    async16(&sBh[t * 8], &Bh[(size_t)(col0 + rr0) * K + k0 + kk0]);
    async16(&sBh[(t + 256) * 8], &Bh[(size_t)(col0 + rr0 + 64) * K + k0 + kk0]);
    async16(&sBl[t * 8], &Bl[(size_t)(col0 + rr0) * K + k0 + kk0]);
    async16(&sBl[(t + 256) * 8], &Bl[(size_t)(col0 + rr0 + 64) * K + k0 + kk0]);
    __syncthreads();
    half8 a_h[4], a_l[4], b_h[4], b_l[4];
#pragma unroll
    for (int i = 0; i < 4; i++) {
      a_h[i] = *(const half8*)&sAh[(wr * 64 + i * 16) * 32 + ar];
      a_l[i] = *(const half8*)&sAl[(wr * 64 + i * 16) * 32 + ar];
      b_h[i] = *(const half8*)&sBh[(wc * 64 + i * 16) * 32 + ar];
      b_l[i] = *(const half8*)&sBl[(wc * 64 + i * 16) * 32 + ar];
    }
#pragma unroll
    for (int i = 0; i < 4; i++)
#pragma unroll
      for (int j = 0; j < 4; j++) {
        acc[i][j] = mfma_f16(a_h[i], b_h[j], acc[i][j]);
        ac2[i][j] = mfma_f16(a_h[i], b_l[j], ac2[i][j]);
        ac2[i][j] = mfma_f16(a_l[i], b_h[j], ac2[i][j]);
      }
  }
  _Float16* strip = &sC[wave * 16 * H_STRIDE];
#pragma unroll
  for (int i = 0; i < 4; i++) {
    size_t gr0 = row0 + wr * 64 + i * 16;
    int gcol0 = col0 + wc * 64;
    float vh[16], vl[16];
#pragma unroll
    for (int j = 0; j < 4; j++) {
      float bv = bias ? bias[gcol0 + j * 16 + (lane & 15)] : 0.0f;
#pragma unroll
      for (int r = 0; r < 4; r++) {
        float v = acc[i][j][r] + ac2[i][j][r] * LO_INV + bv;
        _Float16 hh = (_Float16)v;
        vh[j * 4 + r] = (float)hh;
        vl[j * 4 + r] = (v - (float)hh) * LO_SCALE;
      }
    }
    flush16x64_f16(strip, vh, lane, Ohi, gr0, gcol0, N);
    flush16x64_f16(strip, vl, lane, Olo, gr0, gcol0, N);
  }
}

// 3-pass split GEMM, f32 output, no bias (G2: PQ)
__global__ __launch_bounds__(256) void k_gemm3_f32(
    const _Float16* __restrict__ Ah, const _Float16* __restrict__ Al,
    const _Float16* __restrict__ Bh, const _Float16* __restrict__ Bl,
    float* __restrict__ O, int M, int N, int K) {
  __shared__ _Float16 sAh[128 * 32], sAl[128 * 32], sBh[128 * 32],
      sBl[128 * 32];
  __shared__ float sCf[4 * 16 * F_STRIDE];
  int t = threadIdx.x, lane = t & 63, wave = t >> 6;
  int wr = wave >> 1, wc = wave & 1;
  int row0 = blockIdx.y * 128, col0 = blockIdx.x * 128;
  floatx4 acc[4][4], ac2[4][4];
  for (int i = 0; i < 4; i++)
    for (int j = 0; j < 4; j++) {
      acc[i][j] = (floatx4){0.f, 0.f, 0.f, 0.f};
      ac2[i][j] = (floatx4){0.f, 0.f, 0.f, 0.f};
    }
  int rr0 = t >> 2, kk0 = (t & 3) * 8;
  int ar = (lane & 15) * 32 + (lane >> 4) * 8;
  for (int k0 = 0; k0 < K; k0 += 32) {
    __syncthreads();
    async16(&sAh[t * 8], &Ah[(size_t)(row0 + rr0) * K + k0 + kk0]);
    async16(&sAh[(t + 256) * 8], &Ah[(size_t)(row0 + rr0 + 64) * K + k0 + kk0]);
    async16(&sAl[t * 8], &Al[(size_t)(row0 + rr0) * K + k0 + kk0]);
    async16(&sAl[(t + 256) * 8], &Al[(size_t)(row0 + rr0 + 64) * K + k0 + kk0]);
    async16(&sBh[t * 8], &Bh[(size_t)(col0 + rr0) * K + k0 + kk0]);
    async16(&sBh[(t + 256) * 8], &Bh[(size_t)(col0 + rr0 + 64) * K + k0 + kk0]);
    async16(&sBl[t * 8], &Bl[(size_t)(col0 + rr0) * K + k0 + kk0]);
    async16(&sBl[(t + 256) * 8], &Bl[(size_t)(col0 + rr0 + 64) * K + k0 + kk0]);
    __syncthreads();
    half8 a_h[4], a_l[4], b_h[4], b_l[4];
#pragma unroll
    for (int i = 0; i < 4; i++) {
      a_h[i] = *(const half8*)&sAh[(wr * 64 + i * 16) * 32 + ar];
      a_l[i] = *(const half8*)&sAl[(wr * 64 + i * 16) * 32 + ar];
      b_h[i] = *(const half8*)&sBh[(wc * 64 + i * 16) * 32 + ar];
      b_l[i] = *(const half8*)&sBl[(wc * 64 + i * 16) * 32 + ar];
    }
#pragma unroll
    for (int i = 0; i < 4; i++)
#pragma unroll
      for (int j = 0; j < 4; j++) {
        acc[i][j] = mfma_f16(a_h[i], b_h[j], acc[i][j]);
        ac2[i][j] = mfma_f16(a_h[i], b_l[j], ac2[i][j]);
        ac2[i][j] = mfma_f16(a_l[i], b_h[j], ac2[i][j]);
      }
  }
  float* strip = &sCf[wave * 16 * F_STRIDE];
#pragma unroll
  for (int i = 0; i < 4; i++) {
    size_t gr0 = row0 + wr * 64 + i * 16;
    int gcol0 = col0 + wc * 64;
    float vv[16];
#pragma unroll
    for (int j = 0; j < 4; j++)
#pragma unroll
      for (int r = 0; r < 4; r++)
        vv[j * 4 + r] = acc[i][j][r] + ac2[i][j][r] * LO_INV;
    flush16x64_f32(strip, vv, lane, O, gr0, gcol0, N);
  }
}

// 2-pass GEMM: A single fp16, B split; f32 output + bias (G3: out)
__global__ __launch_bounds__(256) void k_gemm2_out(
    const _Float16* __restrict__ A, const _Float16* __restrict__ Bh,
    const _Float16* __restrict__ Bl, const float* __restrict__ bias,
    float* __restrict__ O, int M, int N, int K) {
  __shared__ _Float16 sA[128 * 32], sBh[128 * 32], sBl[128 * 32];
  __shared__ float sCf[4 * 16 * F_STRIDE];
  int t = threadIdx.x, lane = t & 63, wave = t >> 6;
  int wr = wave >> 1, wc = wave & 1;
  int row0 = blockIdx.y * 128, col0 = blockIdx.x * 128;
  floatx4 acc[4][4], ac2[4][4];
  for (int i = 0; i < 4; i++)
    for (int j = 0; j < 4; j++) {
      acc[i][j] = (floatx4){0.f, 0.f, 0.f, 0.f};
      ac2[i][j] = (floatx4){0.f, 0.f, 0.f, 0.f};
    }
  int rr0 = t >> 2, kk0 = (t & 3) * 8;
  int ar = (lane & 15) * 32 + (lane >> 4) * 8;
  for (int k0 = 0; k0 < K; k0 += 32) {
    __syncthreads();
    async16(&sA[t * 8], &A[(size_t)(row0 + rr0) * K + k0 + kk0]);
    async16(&sA[(t + 256) * 8], &A[(size_t)(row0 + rr0 + 64) * K + k0 + kk0]);
    async16(&sBh[t * 8], &Bh[(size_t)(col0 + rr0) * K + k0 + kk0]);
    async16(&sBh[(t + 256) * 8], &Bh[(size_t)(col0 + rr0 + 64) * K + k0 + kk0]);
    async16(&sBl[t * 8], &Bl[(size_t)(col0 + rr0) * K + k0 + kk0]);
    async16(&sBl[(t + 256) * 8], &Bl[(size_t)(col0 + rr0 + 64) * K + k0 + kk0]);
    __syncthreads();
    half8 a[4], b_h[4], b_l[4];
#pragma unroll
    for (int i = 0; i < 4; i++) {
      a[i] = *(const half8*)&sA[(wr * 64 + i * 16) * 32 + ar];
      b_h[i] = *(const half8*)&sBh[(wc * 64 + i * 16) * 32 + ar];
      b_l[i] = *(const half8*)&sBl[(wc * 64 + i * 16) * 32 + ar];
    }
#pragma unroll
    for (int i = 0; i < 4; i++)
#pragma unroll
      for (int j = 0; j < 4; j++) {
        acc[i][j] = mfma_f16(a[i], b_h[j], acc[i][j]);
        ac2[i][j] = mfma_f16(a[i], b_l[j], ac2[i][j]);
      }
  }
  float* strip = &sCf[wave * 16 * F_STRIDE];
#pragma unroll
  for (int i = 0; i < 4; i++) {
    size_t gr0 = row0 + wr * 64 + i * 16;
    int gcol0 = col0 + wc * 64;
    float vv[16];
#pragma unroll
    for (int j = 0; j < 4; j++) {
      float bv = bias[gcol0 + j * 16 + (lane & 15)];
#pragma unroll
      for (int r = 0; r < 4; r++)
        vv[j * 4 + r] = acc[i][j][r] + ac2[i][j][r] * LO_INV + bv;
    }
    flush16x64_f32(strip, vv, lane, O, gr0, gcol0, N);
  }
}

// ---------------- per-cycle kernels ----------------

// probs = softmax(relu(c*P + Q + br1) @ Wr2 + br2); one wave per row
__global__ __launch_bounds__(256) void k_router(
    const float* __restrict__ PQ, const float* __restrict__ br1,
    const float* __restrict__ Wr2, const float* __restrict__ br2, float cval,
    float* __restrict__ probs) {
  int lane = threadIdx.x & 63;
  int wave = threadIdx.x >> 6;
  int row = blockIdx.x * 4 + wave;
  float4 p4 = ((const float4*)(PQ + (size_t)row * 512))[lane];
  float4 q4 = ((const float4*)(PQ + (size_t)row * 512 + 256))[lane];
  float4 b4 = ((const float4*)br1)[lane];
  float rv[4];
  rv[0] = fmaxf(cval * p4.x + q4.x + b4.x, 0.f);
  rv[1] = fmaxf(cval * p4.y + q4.y + b4.y, 0.f);
  rv[2] = fmaxf(cval * p4.z + q4.z + b4.z, 0.f);
  rv[3] = fmaxf(cval * p4.w + q4.w + b4.w, 0.f);
  float lg[8] = {0.f, 0.f, 0.f, 0.f, 0.f, 0.f, 0.f, 0.f};
#pragma unroll
  for (int k = 0; k < 4; k++) {
    const float4* w = (const float4*)(Wr2 + (size_t)(lane * 4 + k) * 8);
    float4 w0 = w[0], w1 = w[1];
    lg[0] += rv[k] * w0.x;
    lg[1] += rv[k] * w0.y;
    lg[2] += rv[k] * w0.z;
    lg[3] += rv[k] * w0.w;
    lg[4] += rv[k] * w1.x;
    lg[5] += rv[k] * w1.y;
    lg[6] += rv[k] * w1.z;
    lg[7] += rv[k] * w1.w;
  }
#pragma unroll
  for (int s = 32; s > 0; s >>= 1)
#pragma unroll
    for (int m = 0; m < 8; m++) lg[m] += __shfl_xor(lg[m], s);
#pragma unroll
  for (int m = 0; m < 8; m++) lg[m] += br2[m];
  float mx = lg[0];
#pragma unroll
  for (int m = 1; m < 8; m++) mx = fmaxf(mx, lg[m]);
  float e[8];
  float sum = 0.f;
#pragma unroll
  for (int m = 0; m < 8; m++) {
    e[m] = expf(lg[m] - mx);
    sum += e[m];
  }
  float inv = 1.f / sum;
  if (lane < 8) probs[(size_t)row * 8 + lane] = e[lane] * inv;
}

// Per-expert weighted partial GEMM. blockIdx.z = expert m. Epilogue applies
// bias+relu, weights by probs[row][m], LDS-bounce coalesced fp16 store.
__global__ __launch_bounds__(256) void k_expert_partial(
    const _Float16* __restrict__ hin, const _Float16* __restrict__ WT,
    const float* __restrict__ bmod, const float* __restrict__ probs,
    _Float16* __restrict__ part, int rowbase) {
  __shared__ _Float16 sA[128 * 32];
  __shared__ _Float16 sB[128 * 32];
  __shared__ _Float16 sC[4 * 16 * H_STRIDE];
  __shared__ float sProb[128];
  __shared__ float sBias[128];
  const int K = 1024;
  int t = threadIdx.x, lane = t & 63, wave = t >> 6;
  int wr = wave >> 1, wc = wave & 1;
  int m = blockIdx.z;
  int col0 = blockIdx.x * 128;
  int prow0 = blockIdx.y * 128;
  int grow0 = rowbase + prow0;
  if (t < 128)
    sProb[t] = probs[(size_t)(grow0 + t) * 8 + m];
  else
    sBias[t - 128] = bmod[(size_t)m * 1024 + col0 + (t - 128)];
  const _Float16* Bm = WT + (size_t)m * 1024 * 1024;
  floatx4 acc[4][4];
  for (int i = 0; i < 4; i++)
    for (int j = 0; j < 4; j++) acc[i][j] = (floatx4){0.f, 0.f, 0.f, 0.f};
  int rr0 = t >> 2, kk0 = (t & 3) * 8;
  int ar = (lane & 15) * 32 + (lane >> 4) * 8;
  for (int k0 = 0; k0 < K; k0 += 32) {
    __syncthreads();
    async16(&sA[t * 8], &hin[(size_t)(grow0 + rr0) * K + k0 + kk0]);
    async16(&sA[(t + 256) * 8],
            &hin[(size_t)(grow0 + rr0 + 64) * K + k0 + kk0]);
    async16(&sB[t * 8], &Bm[(size_t)(col0 + rr0) * K + k0 + kk0]);
    async16(&sB[(t + 256) * 8], &Bm[(size_t)(col0 + rr0 + 64) * K + k0 + kk0]);
    __syncthreads();
    half8 a[4], b[4];
#pragma unroll
    for (int i = 0; i < 4; i++) {
      a[i] = *(const half8*)&sA[(wr * 64 + i * 16) * 32 + ar];
      b[i] = *(const half8*)&sB[(wc * 64 + i * 16) * 32 + ar];
    }
#pragma unroll
    for (int i = 0; i < 4; i++)
#pragma unroll
      for (int j = 0; j < 4; j++) acc[i][j] = mfma_f16(a[i], b[j], acc[i][j]);
  }
  _Float16* strip = &sC[wave * 16 * H_STRIDE];
#pragma unroll
  for (int i = 0; i < 4; i++) {
    int lr0 = wr * 64 + i * 16 + ((lane >> 4) << 2);
    float pr[4] = {sProb[lr0 + 0], sProb[lr0 + 1], sProb[lr0 + 2],
                   sProb[lr0 + 3]};
    float vv[16];
#pragma unroll
    for (int j = 0; j < 4; j++) {
      float bb = sBias[wc * 64 + j * 16 + (lane & 15)];
#pragma unroll
      for (int r = 0; r < 4; r++)
        vv[j * 4 + r] = pr[r] * fmaxf(acc[i][j][r] + bb, 0.f);
    }
    size_t gr0 = (size_t)m * 4096 + (size_t)(prow0 + wr * 64 + i * 16);
    flush16x64_f16(strip, vv, lane, part, gr0, col0 + wc * 64, 1024);
  }
}

// sum 8 expert slabs (fp16) -> hout rows [rowbase, rowbase+4096)
__global__ __launch_bounds__(256) void k_combine8(
    const _Float16* __restrict__ part, _Float16* __restrict__ hout,
    int rowbase) {
  const size_t S = (size_t)4096 * 1024;
  size_t i = ((size_t)blockIdx.x * 256 + threadIdx.x) * 8;
  float s[8] = {0.f, 0.f, 0.f, 0.f, 0.f, 0.f, 0.f, 0.f};
#pragma unroll
  for (int m = 0; m < 8; m++) {
    half8 v = *(const half8*)&part[(size_t)m * S + i];
#pragma unroll
    for (int k = 0; k < 8; k++) s[k] += (float)v[k];
  }
  half8 o;
#pragma unroll
  for (int k = 0; k < 8; k++) o[k] = (_Float16)s[k];
  *(half8*)&hout[(size_t)rowbase * 1024 + i] = o;
}

// ---------------- launcher ----------------

extern "C" void kernel_launch(void* const* d_in, const int* in_sizes, int n_in,
                              void* d_out, int out_size, void* d_ws,
                              size_t ws_size, hipStream_t stream) {
  (void)in_sizes;
  (void)n_in;
  (void)out_size;
  (void)ws_size;
  const float* x = (const float*)d_in[0];
  const float* W_in = (const float*)d_in[1];
  const float* b_in = (const float*)d_in[2];
  const float* W_mod = (const float*)d_in[3];
  const float* b_mod = (const float*)d_in[4];
  const float* Wr1 = (const float*)d_in[5];
  const float* br1 = (const float*)d_in[6];
  const float* Wr2 = (const float*)d_in[7];
  const float* br2 = (const float*)d_in[8];
  const float* Wc = (const float*)d_in[9];
  const float* bc = (const float*)d_in[10];
  const float* W_out = (const float*)d_in[11];
  const float* b_out = (const float*)d_in[12];
  float* out = (float*)d_out;

  const int B = 16384, IN = 512, H = 1024, OUT = 512, M = 8, R = 256;
  const size_t MB = 1024 * 1024;

  char* p = (char*)d_ws;
  _Float16* partial = (_Float16*)(p + 0);      // 64 MB (cycles only)
  _Float16* origLo = (_Float16*)(p + 0);       // 32 MB (prep/G1/G2 only)
  _Float16* xh = (_Float16*)(p + 32 * MB);     // 16 MB
  _Float16* xl = (_Float16*)(p + 48 * MB);     // 16 MB
  _Float16* WinTh = (_Float16*)(p + 64 * MB);  // 1 MB
  _Float16* WinTl = (_Float16*)(p + 65 * MB);  // 1 MB
  _Float16* W1Th = (_Float16*)(p + 66 * MB);   // 1 MB  [2R][H] merged
  _Float16* W1Tl = (_Float16*)(p + 67 * MB);   // 1 MB
  _Float16* WoutTh = (_Float16*)(p + 68 * MB); // 1 MB
  _Float16* WoutTl = (_Float16*)(p + 69 * MB); // 1 MB
  _Float16* WmodT = (_Float16*)(p + 70 * MB);  // 16 MB
  _Float16* origHi = (_Float16*)(p + 86 * MB); // 32 MB
  _Float16* hA = (_Float16*)(p + 118 * MB);    // 32 MB
  _Float16* hB = (_Float16*)(p + 150 * MB);    // 32 MB
  float* PQ = (float*)(p + 182 * MB);          // 32 MB  [B][512]
  float* probs = (float*)(p + 214 * MB);       // 0.5 MB

  // prep
  k_split<<<dim3((B * IN / 4 + 255) / 256), dim3(256), 0, stream>>>(
      x, xh, xl, B * IN / 4);
  k_transpose_split<<<dim3(H / 64, IN / 64, 1), dim3(256), 0, stream>>>(
      W_in, nullptr, WinTh, WinTl, IN, H);
  k_transpose_split<<<dim3(R / 64, H / 64, 1), dim3(256), 0, stream>>>(
      Wr1, Wc, W1Th, W1Tl, H, R);
  k_transpose_split<<<dim3(R / 64, H / 64, 1), dim3(256), 0, stream>>>(
      Wr1, bc, W1Th + (size_t)R * H, W1Tl + (size_t)R * H, H, R);
  k_transpose_split<<<dim3(OUT / 64, H / 64, 1), dim3(256), 0, stream>>>(
      W_out, nullptr, WoutTh, WoutTl, H, OUT);
  k_transpose_split<<<dim3(H / 64, H / 64, M), dim3(256), 0, stream>>>(
      W_mod, nullptr, WmodT, nullptr, H, H);

  // G1: orig = x@W_in + b_in
  k_gemm3_split<<<dim3(H / 128, B / 128), dim3(256), 0, stream>>>(
      xh, xl, WinTh, WinTl, b_in, origHi, origLo, B, H, IN);
  // G2: PQ = orig@[diag(Wc)Wr1 | diag(bc)Wr1]
  k_gemm3_f32<<<dim3(2 * R / 128, B / 128), dim3(256), 0, stream>>>(
      origHi, origLo, W1Th, W1Tl, PQ, B, 2 * R, H);

  // 4 cycles (max_cycles == 4 from setup_inputs), row-chunked x4
  const _Float16* hcur = origHi;
  _Float16* hbufs[2] = {hA, hB};
  for (int c = 0; c < 4; c++) {
    k_router<<<dim3(B / 4), dim3(256), 0, stream>>>(PQ, br1, Wr2, br2, (float)c,
                                                    probs);
    _Float16* hn = hbufs[c & 1];
    for (int chunk = 0; chunk < 4; chunk++) {
      int rowbase = chunk * 4096;
      k_expert_partial<<<dim3(H / 128, 32, M), dim3(256), 0, stream>>>(
          hcur, WmodT, b_mod, probs, partial, rowbase);
      k_combine8<<<dim3(4096 * 1024 / (256 * 8)), dim3(256), 0, stream>>>(
          partial, hn, rowbase);
    }
    hcur = hn;
  }

  // G3: out = h@W_out + b_out
  k_gemm2_out<<<dim3(OUT / 128, B / 128), dim3(256), 0, stream>>>(
      hcur, WoutTh, WoutTl, b_out, out, B, OUT, H);
}

// Round 4
// 1906.749 us; speedup vs baseline: 1.1530x; 1.1530x over previous
//
#include <hip/hip_runtime.h>

// Router_15942918603252 — MI355X implementation (R4).
// R4: all GEMMs plain fp16 single-pass (R3 post-mortem: split passes were
// precision overkill — expert chain already consumes plain-fp16 h; router
// Jacobian amplifies orig error only ~2x). LDS-bounce epilogue reverted
// (R3 showed it was a net loss; stores were already full-line at L2).
// Router probs for all 4 cycles computed in one dispatch (PQ is c-independent).
//
// Pipeline: prep (fp16 cast / transposes) -> G1 orig = x@W_in+b_in ->
// G2 PQ = orig@[diag(Wc)Wr1 | diag(bc)Wr1] -> router4 (all cycles) ->
// 4x { per-expert weighted partial GEMMs (grid.z=m, row-chunked x4);
//      combine8 } -> G3 out = h@W_out + b_out.
// max_cycles==4 hardcoded (setup_inputs constant).

typedef _Float16 half8 __attribute__((ext_vector_type(8)));
typedef _Float16 half4v __attribute__((ext_vector_type(4)));
typedef float floatx4 __attribute__((ext_vector_type(4)));

#define DEVI __device__ __forceinline__

DEVI void async16(void* lds, const void* g) {
  __builtin_amdgcn_global_load_lds(
      (const __attribute__((address_space(1))) unsigned int*)g,
      (__attribute__((address_space(3))) unsigned int*)lds, 16, 0, 0);
}

DEVI floatx4 mfma_f16(half8 a, half8 b, floatx4 c) {
  return __builtin_amdgcn_mfma_f32_16x16x32_f16(a, b, c, 0, 0, 0);
}

// ---------------- prep kernels ----------------

// f32 -> fp16 cast, vectorized by 4
__global__ __launch_bounds__(256) void k_cast16(const float* __restrict__ in,
                                                _Float16* __restrict__ o,
                                                int n4) {
  int i = blockIdx.x * 256 + threadIdx.x;
  if (i >= n4) return;
  float4 v = ((const float4*)in)[i];
  half4v h;
  h[0] = (_Float16)v.x;
  h[1] = (_Float16)v.y;
  h[2] = (_Float16)v.z;
  h[3] = (_Float16)v.w;
  ((half4v*)o)[i] = h;
}

// in: [batch][R][C] f32; optional per-input-row scale[r]. out: [batch][C][R]
// fp16 (transposed, k-contiguous for MFMA B-frags).
__global__ __launch_bounds__(256) void k_transpose16(
    const float* __restrict__ in, const float* __restrict__ scale,
    _Float16* __restrict__ o, int R, int C) {
  __shared__ float tile[64][65];
  __shared__ float srow[64];
  int b = blockIdx.z;
  int r0 = blockIdx.y * 64, c0 = blockIdx.x * 64;
  const float* src = in + (size_t)b * R * C;
  int t = threadIdx.x;
  int lr = t >> 4;
  int lc4 = (t & 15) * 4;
#pragma unroll
  for (int rr = 0; rr < 64; rr += 16) {
    float4 v = *(const float4*)&src[(size_t)(r0 + lr + rr) * C + c0 + lc4];
    tile[lr + rr][lc4 + 0] = v.x;
    tile[lr + rr][lc4 + 1] = v.y;
    tile[lr + rr][lc4 + 2] = v.z;
    tile[lr + rr][lc4 + 3] = v.w;
  }
  if (t < 64) srow[t] = scale ? scale[r0 + t] : 1.0f;
  __syncthreads();
  int oc = t >> 2;
  int orr = (t & 3) * 16;
  alignas(16) _Float16 hv[16];
#pragma unroll
  for (int k = 0; k < 16; k++)
    hv[k] = (_Float16)(tile[orr + k][oc] * srow[orr + k]);
  size_t ob = (size_t)b * C * R + (size_t)(c0 + oc) * R + (r0 + orr);
  ((int4*)&o[ob])[0] = ((int4*)hv)[0];
  ((int4*)&o[ob])[1] = ((int4*)hv)[1];
}

// ---------------- GEMM kernels (m97 structure: 128x128 tile, 4 waves) -------

// O_fp16 = A[M][K] @ Bt[N][K]^T (+ bias)
__global__ __launch_bounds__(256) void k_gemm_f16(
    const _Float16* __restrict__ A, const _Float16* __restrict__ Bt,
    const float* __restrict__ bias, _Float16* __restrict__ O, int M, int N,
    int K) {
  __shared__ _Float16 sA[128 * 32], sB[128 * 32];
  int t = threadIdx.x, lane = t & 63, wave = t >> 6;
  int wr = wave >> 1, wc = wave & 1;
  int row0 = blockIdx.y * 128, col0 = blockIdx.x * 128;
  floatx4 acc[4][4];
  for (int i = 0; i < 4; i++)
    for (int j = 0; j < 4; j++) acc[i][j] = (floatx4){0.f, 0.f, 0.f, 0.f};
  int rr0 = t >> 2, kk0 = (t & 3) * 8;
  int ar = (lane & 15) * 32 + (lane >> 4) * 8;
  for (int k0 = 0; k0 < K; k0 += 32) {
    __syncthreads();
    async16(&sA[t * 8], &A[(size_t)(row0 + rr0) * K + k0 + kk0]);
    async16(&sA[(t + 256) * 8], &A[(size_t)(row0 + rr0 + 64) * K + k0 + kk0]);
    async16(&sB[t * 8], &Bt[(size_t)(col0 + rr0) * K + k0 + kk0]);
    async16(&sB[(t + 256) * 8], &Bt[(size_t)(col0 + rr0 + 64) * K + k0 + kk0]);
    __syncthreads();
    half8 a[4], b[4];
#pragma unroll
    for (int i = 0; i < 4; i++) {
      a[i] = *(const half8*)&sA[(wr * 64 + i * 16) * 32 + ar];
      b[i] = *(const half8*)&sB[(wc * 64 + i * 16) * 32 + ar];
    }
#pragma unroll
    for (int i = 0; i < 4; i++)
#pragma unroll
      for (int j = 0; j < 4; j++) acc[i][j] = mfma_f16(a[i], b[j], acc[i][j]);
  }
#pragma unroll
  for (int i = 0; i < 4; i++) {
    int rowb = row0 + wr * 64 + i * 16 + ((lane >> 4) << 2);
#pragma unroll
    for (int j = 0; j < 4; j++) {
      int col = col0 + wc * 64 + j * 16 + (lane & 15);
      float bv = bias ? bias[col] : 0.0f;
#pragma unroll
      for (int r = 0; r < 4; r++)
        O[(size_t)(rowb + r) * N + col] = (_Float16)(acc[i][j][r] + bv);
    }
  }
}

// O_f32 = A[M][K] @ Bt[N][K]^T (+ bias)
__global__ __launch_bounds__(256) void k_gemm_f32(
    const _Float16* __restrict__ A, const _Float16* __restrict__ Bt,
    const float* __restrict__ bias, float* __restrict__ O, int M, int N,
    int K) {
  __shared__ _Float16 sA[128 * 32], sB[128 * 32];
  int t = threadIdx.x, lane = t & 63, wave = t >> 6;
  int wr = wave >> 1, wc = wave & 1;
  int row0 = blockIdx.y * 128, col0 = blockIdx.x * 128;
  floatx4 acc[4][4];
  for (int i = 0; i < 4; i++)
    for (int j = 0; j < 4; j++) acc[i][j] = (floatx4){0.f, 0.f, 0.f, 0.f};
  int rr0 = t >> 2, kk0 = (t & 3) * 8;
  int ar = (lane & 15) * 32 + (lane >> 4) * 8;
  for (int k0 = 0; k0 < K; k0 += 32) {
    __syncthreads();
    async16(&sA[t * 8], &A[(size_t)(row0 + rr0) * K + k0 + kk0]);
    async16(&sA[(t + 256) * 8], &A[(size_t)(row0 + rr0 + 64) * K + k0 + kk0]);
    async16(&sB[t * 8], &Bt[(size_t)(col0 + rr0) * K + k0 + kk0]);
    async16(&sB[(t + 256) * 8], &Bt[(size_t)(col0 + rr0 + 64) * K + k0 + kk0]);
    __syncthreads();
    half8 a[4], b[4];
#pragma unroll
    for (int i = 0; i < 4; i++) {
      a[i] = *(const half8*)&sA[(wr * 64 + i * 16) * 32 + ar];
      b[i] = *(const half8*)&sB[(wc * 64 + i * 16) * 32 + ar];
    }
#pragma unroll
    for (int i = 0; i < 4; i++)
#pragma unroll
      for (int j = 0; j < 4; j++) acc[i][j] = mfma_f16(a[i], b[j], acc[i][j]);
  }
#pragma unroll
  for (int i = 0; i < 4; i++) {
    int rowb = row0 + wr * 64 + i * 16 + ((lane >> 4) << 2);
#pragma unroll
    for (int j = 0; j < 4; j++) {
      int col = col0 + wc * 64 + j * 16 + (lane & 15);
      float bv = bias ? bias[col] : 0.0f;
#pragma unroll
      for (int r = 0; r < 4; r++)
        O[(size_t)(rowb + r) * N + col] = acc[i][j][r] + bv;
    }
  }
}

// ---------------- router (all 4 cycles in one dispatch) ----------------

// probs[c][row][m] = softmax(relu(c*P + Q + br1) @ Wr2 + br2)
// PQ layout: [row][0..255]=P, [row][256..511]=Q. blockIdx.y = c.
__global__ __launch_bounds__(256) void k_router4(
    const float* __restrict__ PQ, const float* __restrict__ br1,
    const float* __restrict__ Wr2, const float* __restrict__ br2,
    float* __restrict__ probs, int B) {
  int lane = threadIdx.x & 63;
  int wave = threadIdx.x >> 6;
  int row = blockIdx.x * 4 + wave;
  float cval = (float)blockIdx.y;
  float4 p4 = ((const float4*)(PQ + (size_t)row * 512))[lane];
  float4 q4 = ((const float4*)(PQ + (size_t)row * 512 + 256))[lane];
  float4 b4 = ((const float4*)br1)[lane];
  float rv[4];
  rv[0] = fmaxf(cval * p4.x + q4.x + b4.x, 0.f);
  rv[1] = fmaxf(cval * p4.y + q4.y + b4.y, 0.f);
  rv[2] = fmaxf(cval * p4.z + q4.z + b4.z, 0.f);
  rv[3] = fmaxf(cval * p4.w + q4.w + b4.w, 0.f);
  float lg[8] = {0.f, 0.f, 0.f, 0.f, 0.f, 0.f, 0.f, 0.f};
#pragma unroll
  for (int k = 0; k < 4; k++) {
    const float4* w = (const float4*)(Wr2 + (size_t)(lane * 4 + k) * 8);
    float4 w0 = w[0], w1 = w[1];
    lg[0] += rv[k] * w0.x;
    lg[1] += rv[k] * w0.y;
    lg[2] += rv[k] * w0.z;
    lg[3] += rv[k] * w0.w;
    lg[4] += rv[k] * w1.x;
    lg[5] += rv[k] * w1.y;
    lg[6] += rv[k] * w1.z;
    lg[7] += rv[k] * w1.w;
  }
#pragma unroll
  for (int s = 32; s > 0; s >>= 1)
#pragma unroll
    for (int m = 0; m < 8; m++) lg[m] += __shfl_xor(lg[m], s);
#pragma unroll
  for (int m = 0; m < 8; m++) lg[m] += br2[m];
  float mx = lg[0];
#pragma unroll
  for (int m = 1; m < 8; m++) mx = fmaxf(mx, lg[m]);
  float e[8];
  float sum = 0.f;
#pragma unroll
  for (int m = 0; m < 8; m++) {
    e[m] = expf(lg[m] - mx);
    sum += e[m];
  }
  float inv = 1.f / sum;
  if (lane < 8)
    probs[(size_t)blockIdx.y * B * 8 + (size_t)row * 8 + lane] = e[lane] * inv;
}

// ---------------- expert kernels ----------------

// Per-expert weighted partial GEMM. blockIdx.z = expert m. Epilogue applies
// bias+relu, weights by probs[row][m], writes fp16 partial slab
// part[m][4096][1024]. (Scalar-store epilogue — R3's LDS bounce regressed.)
__global__ __launch_bounds__(256) void k_expert_partial(
    const _Float16* __restrict__ hin, const _Float16* __restrict__ WT,
    const float* __restrict__ bmod, const float* __restrict__ probs,
    _Float16* __restrict__ part, int rowbase) {
  __shared__ _Float16 sA[128 * 32];
  __shared__ _Float16 sB[128 * 32];
  __shared__ float sProb[128];
  __shared__ float sBias[128];
  const int K = 1024;
  int t = threadIdx.x, lane = t & 63, wave = t >> 6;
  int wr = wave >> 1, wc = wave & 1;
  int m = blockIdx.z;
  int col0 = blockIdx.x * 128;
  int prow0 = blockIdx.y * 128;
  int grow0 = rowbase + prow0;
  if (t < 128)
    sProb[t] = probs[(size_t)(grow0 + t) * 8 + m];
  else
    sBias[t - 128] = bmod[(size_t)m * 1024 + col0 + (t - 128)];
  const _Float16* Bm = WT + (size_t)m * 1024 * 1024;
  floatx4 acc[4][4];
  for (int i = 0; i < 4; i++)
    for (int j = 0; j < 4; j++) acc[i][j] = (floatx4){0.f, 0.f, 0.f, 0.f};
  int rr0 = t >> 2, kk0 = (t & 3) * 8;
  int ar = (lane & 15) * 32 + (lane >> 4) * 8;
  for (int k0 = 0; k0 < K; k0 += 32) {
    __syncthreads();
    async16(&sA[t * 8], &hin[(size_t)(grow0 + rr0) * K + k0 + kk0]);
    async16(&sA[(t + 256) * 8],
            &hin[(size_t)(grow0 + rr0 + 64) * K + k0 + kk0]);
    async16(&sB[t * 8], &Bm[(size_t)(col0 + rr0) * K + k0 + kk0]);
    async16(&sB[(t + 256) * 8], &Bm[(size_t)(col0 + rr0 + 64) * K + k0 + kk0]);
    __syncthreads();
    half8 a[4], b[4];
#pragma unroll
    for (int i = 0; i < 4; i++) {
      a[i] = *(const half8*)&sA[(wr * 64 + i * 16) * 32 + ar];
      b[i] = *(const half8*)&sB[(wc * 64 + i * 16) * 32 + ar];
    }
#pragma unroll
    for (int i = 0; i < 4; i++)
#pragma unroll
      for (int j = 0; j < 4; j++) acc[i][j] = mfma_f16(a[i], b[j], acc[i][j]);
  }
#pragma unroll
  for (int i = 0; i < 4; i++) {
    int lr0 = wr * 64 + i * 16 + ((lane >> 4) << 2);
    float p0 = sProb[lr0 + 0];
    float p1 = sProb[lr0 + 1];
    float p2 = sProb[lr0 + 2];
    float p3 = sProb[lr0 + 3];
#pragma unroll
    for (int j = 0; j < 4; j++) {
      int cl = wc * 64 + j * 16 + (lane & 15);
      float bb = sBias[cl];
      size_t base =
          (size_t)m * 4096 * 1024 + (size_t)(prow0 + lr0) * 1024 + col0 + cl;
      part[base + 0 * 1024] = (_Float16)(p0 * fmaxf(acc[i][j][0] + bb, 0.f));
      part[base + 1 * 1024] = (_Float16)(p1 * fmaxf(acc[i][j][1] + bb, 0.f));
      part[base + 2 * 1024] = (_Float16)(p2 * fmaxf(acc[i][j][2] + bb, 0.f));
      part[base + 3 * 1024] = (_Float16)(p3 * fmaxf(acc[i][j][3] + bb, 0.f));
    }
  }
}

// sum 8 expert slabs (fp16) -> hout rows [rowbase, rowbase+4096)
__global__ __launch_bounds__(256) void k_combine8(
    const _Float16* __restrict__ part, _Float16* __restrict__ hout,
    int rowbase) {
  const size_t S = (size_t)4096 * 1024;
  size_t i = ((size_t)blockIdx.x * 256 + threadIdx.x) * 8;
  float s[8] = {0.f, 0.f, 0.f, 0.f, 0.f, 0.f, 0.f, 0.f};
#pragma unroll
  for (int m = 0; m < 8; m++) {
    half8 v = *(const half8*)&part[(size_t)m * S + i];
#pragma unroll
    for (int k = 0; k < 8; k++) s[k] += (float)v[k];
  }
  half8 o;
#pragma unroll
  for (int k = 0; k < 8; k++) o[k] = (_Float16)s[k];
  *(half8*)&hout[(size_t)rowbase * 1024 + i] = o;
}

// ---------------- launcher ----------------

extern "C" void kernel_launch(void* const* d_in, const int* in_sizes, int n_in,
                              void* d_out, int out_size, void* d_ws,
                              size_t ws_size, hipStream_t stream) {
  (void)in_sizes;
  (void)n_in;
  (void)out_size;
  (void)ws_size;
  const float* x = (const float*)d_in[0];
  const float* W_in = (const float*)d_in[1];
  const float* b_in = (const float*)d_in[2];
  const float* W_mod = (const float*)d_in[3];
  const float* b_mod = (const float*)d_in[4];
  const float* Wr1 = (const float*)d_in[5];
  const float* br1 = (const float*)d_in[6];
  const float* Wr2 = (const float*)d_in[7];
  const float* br2 = (const float*)d_in[8];
  const float* Wc = (const float*)d_in[9];
  const float* bc = (const float*)d_in[10];
  const float* W_out = (const float*)d_in[11];
  const float* b_out = (const float*)d_in[12];
  float* out = (float*)d_out;

  const int B = 16384, IN = 512, H = 1024, OUT = 512, M = 8, R = 256;
  const size_t MB = 1024 * 1024;

  char* p = (char*)d_ws;
  // partial (64 MB, cycles only) aliases xh (16 MB, dead after G1)
  _Float16* partial = (_Float16*)(p + 0);       // 64 MB
  _Float16* xh = (_Float16*)(p + 0);            // 16 MB
  _Float16* WinT = (_Float16*)(p + 64 * MB);    // 1 MB  [H][IN]
  _Float16* W1T = (_Float16*)(p + 65 * MB);     // 1 MB  [2R][H]
  _Float16* WoutT = (_Float16*)(p + 66 * MB);   // 1 MB  [OUT][H]
  _Float16* WmodT = (_Float16*)(p + 67 * MB);   // 16 MB [M][H][H]
  _Float16* origHi = (_Float16*)(p + 83 * MB);  // 32 MB [B][H]
  _Float16* hA = (_Float16*)(p + 115 * MB);     // 32 MB
  _Float16* hB = (_Float16*)(p + 147 * MB);     // 32 MB
  float* PQ = (float*)(p + 179 * MB);           // 32 MB [B][512]
  float* probs4 = (float*)(p + 211 * MB);       // 2 MB  [4][B][8]

  // prep
  k_cast16<<<dim3(B * IN / 4 / 256), dim3(256), 0, stream>>>(x, xh,
                                                             B * IN / 4);
  k_transpose16<<<dim3(H / 64, IN / 64, 1), dim3(256), 0, stream>>>(
      W_in, nullptr, WinT, IN, H);
  k_transpose16<<<dim3(R / 64, H / 64, 1), dim3(256), 0, stream>>>(
      Wr1, Wc, W1T, H, R);
  k_transpose16<<<dim3(R / 64, H / 64, 1), dim3(256), 0, stream>>>(
      Wr1, bc, W1T + (size_t)R * H, H, R);
  k_transpose16<<<dim3(OUT / 64, H / 64, 1), dim3(256), 0, stream>>>(
      W_out, nullptr, WoutT, H, OUT);
  k_transpose16<<<dim3(H / 64, H / 64, M), dim3(256), 0, stream>>>(
      W_mod, nullptr, WmodT, H, H);

  // G1: orig = x@W_in + b_in   [B][H] fp16
  k_gemm_f16<<<dim3(H / 128, B / 128), dim3(256), 0, stream>>>(
      xh, WinT, b_in, origHi, B, H, IN);
  // G2: PQ = orig@[diag(Wc)Wr1 | diag(bc)Wr1]   [B][512] f32
  k_gemm_f32<<<dim3(2 * R / 128, B / 128), dim3(256), 0, stream>>>(
      origHi, W1T, nullptr, PQ, B, 2 * R, H);
  // router: all 4 cycles' probs in one dispatch
  k_router4<<<dim3(B / 4, 4), dim3(256), 0, stream>>>(PQ, br1, Wr2, br2,
                                                      probs4, B);

  // 4 cycles (max_cycles == 4 from setup_inputs), row-chunked x4
  const _Float16* hcur = origHi;
  _Float16* hbufs[2] = {hA, hB};
  for (int c = 0; c < 4; c++) {
    const float* probs = probs4 + (size_t)c * B * 8;
    _Float16* hn = hbufs[c & 1];
    for (int chunk = 0; chunk < 4; chunk++) {
      int rowbase = chunk * 4096;
      k_expert_partial<<<dim3(H / 128, 32, M), dim3(256), 0, stream>>>(
          hcur, WmodT, b_mod, probs, partial, rowbase);
      k_combine8<<<dim3(4096 * 1024 / (256 * 8)), dim3(256), 0, stream>>>(
          partial, hn, rowbase);
    }
    hcur = hn;
  }

  // G3: out = h@W_out + b_out   [B][OUT] f32
  k_gemm_f32<<<dim3(OUT / 128, B / 128), dim3(256), 0, stream>>>(
      hcur, WoutT, b_out, out, B, OUT, H);
}

// Round 5
// 1757.658 us; speedup vs baseline: 1.2508x; 1.0848x over previous
//
#include <hip/hip_runtime.h>

// Router_15942918603252 — MI355X implementation (R5).
// R5: expert kernel restructured for arithmetic intensity. R4 post-mortem:
// expert GEMM is staging/LDS-BW-bound (16 KB staged + 32 KB LDS-read per 16
// MFMA; MfmaUtil 30%). New k_expert_pair: 512 threads, tile 256 rows x 128
// cols x 2 experts (z, z+4) sharing one staged A tile -> intensity 128 vs 64
// MAC/byte. Each wave computes 64x64 for BOTH experts, sums the weighted
// relus in registers -> 4 partial slabs instead of 8 -> combine halves.
//
// Pipeline: prep (fp16 cast/transposes) -> G1 orig = x@W_in+b_in ->
// G2 PQ = orig@[diag(Wc)Wr1 | diag(bc)Wr1] -> router4 (all 4 cycles) ->
// 4x { 2 row-chunks x (k_expert_pair; k_combine4) } -> G3 out.
// max_cycles==4 hardcoded (setup_inputs constant).

typedef _Float16 half8 __attribute__((ext_vector_type(8)));
typedef _Float16 half4v __attribute__((ext_vector_type(4)));
typedef float floatx4 __attribute__((ext_vector_type(4)));

#define DEVI __device__ __forceinline__
#define CHUNK 8192

DEVI void async16(void* lds, const void* g) {
  __builtin_amdgcn_global_load_lds(
      (const __attribute__((address_space(1))) unsigned int*)g,
      (__attribute__((address_space(3))) unsigned int*)lds, 16, 0, 0);
}

DEVI floatx4 mfma_f16(half8 a, half8 b, floatx4 c) {
  return __builtin_amdgcn_mfma_f32_16x16x32_f16(a, b, c, 0, 0, 0);
}

// ---------------- prep kernels ----------------

__global__ __launch_bounds__(256) void k_cast16(const float* __restrict__ in,
                                                _Float16* __restrict__ o,
                                                int n4) {
  int i = blockIdx.x * 256 + threadIdx.x;
  if (i >= n4) return;
  float4 v = ((const float4*)in)[i];
  half4v h;
  h[0] = (_Float16)v.x;
  h[1] = (_Float16)v.y;
  h[2] = (_Float16)v.z;
  h[3] = (_Float16)v.w;
  ((half4v*)o)[i] = h;
}

// in: [batch][R][C] f32; optional per-input-row scale[r]. out: [batch][C][R]
__global__ __launch_bounds__(256) void k_transpose16(
    const float* __restrict__ in, const float* __restrict__ scale,
    _Float16* __restrict__ o, int R, int C) {
  __shared__ float tile[64][65];
  __shared__ float srow[64];
  int b = blockIdx.z;
  int r0 = blockIdx.y * 64, c0 = blockIdx.x * 64;
  const float* src = in + (size_t)b * R * C;
  int t = threadIdx.x;
  int lr = t >> 4;
  int lc4 = (t & 15) * 4;
#pragma unroll
  for (int rr = 0; rr < 64; rr += 16) {
    float4 v = *(const float4*)&src[(size_t)(r0 + lr + rr) * C + c0 + lc4];
    tile[lr + rr][lc4 + 0] = v.x;
    tile[lr + rr][lc4 + 1] = v.y;
    tile[lr + rr][lc4 + 2] = v.z;
    tile[lr + rr][lc4 + 3] = v.w;
  }
  if (t < 64) srow[t] = scale ? scale[r0 + t] : 1.0f;
  __syncthreads();
  int oc = t >> 2;
  int orr = (t & 3) * 16;
  alignas(16) _Float16 hv[16];
#pragma unroll
  for (int k = 0; k < 16; k++)
    hv[k] = (_Float16)(tile[orr + k][oc] * srow[orr + k]);
  size_t ob = (size_t)b * C * R + (size_t)(c0 + oc) * R + (r0 + orr);
  ((int4*)&o[ob])[0] = ((int4*)hv)[0];
  ((int4*)&o[ob])[1] = ((int4*)hv)[1];
}

// ---------------- generic GEMMs (m97 structure, 128x128, 4 waves) ----------

__global__ __launch_bounds__(256) void k_gemm_f16(
    const _Float16* __restrict__ A, const _Float16* __restrict__ Bt,
    const float* __restrict__ bias, _Float16* __restrict__ O, int M, int N,
    int K) {
  __shared__ _Float16 sA[128 * 32], sB[128 * 32];
  int t = threadIdx.x, lane = t & 63, wave = t >> 6;
  int wr = wave >> 1, wc = wave & 1;
  int row0 = blockIdx.y * 128, col0 = blockIdx.x * 128;
  floatx4 acc[4][4];
  for (int i = 0; i < 4; i++)
    for (int j = 0; j < 4; j++) acc[i][j] = (floatx4){0.f, 0.f, 0.f, 0.f};
  int rr0 = t >> 2, kk0 = (t & 3) * 8;
  int ar = (lane & 15) * 32 + (lane >> 4) * 8;
  for (int k0 = 0; k0 < K; k0 += 32) {
    __syncthreads();
    async16(&sA[t * 8], &A[(size_t)(row0 + rr0) * K + k0 + kk0]);
    async16(&sA[(t + 256) * 8], &A[(size_t)(row0 + rr0 + 64) * K + k0 + kk0]);
    async16(&sB[t * 8], &Bt[(size_t)(col0 + rr0) * K + k0 + kk0]);
    async16(&sB[(t + 256) * 8], &Bt[(size_t)(col0 + rr0 + 64) * K + k0 + kk0]);
    __syncthreads();
    half8 a[4], b[4];
#pragma unroll
    for (int i = 0; i < 4; i++) {
      a[i] = *(const half8*)&sA[(wr * 64 + i * 16) * 32 + ar];
      b[i] = *(const half8*)&sB[(wc * 64 + i * 16) * 32 + ar];
    }
#pragma unroll
    for (int i = 0; i < 4; i++)
#pragma unroll
      for (int j = 0; j < 4; j++) acc[i][j] = mfma_f16(a[i], b[j], acc[i][j]);
  }
#pragma unroll
  for (int i = 0; i < 4; i++) {
    int rowb = row0 + wr * 64 + i * 16 + ((lane >> 4) << 2);
#pragma unroll
    for (int j = 0; j < 4; j++) {
      int col = col0 + wc * 64 + j * 16 + (lane & 15);
      float bv = bias ? bias[col] : 0.0f;
#pragma unroll
      for (int r = 0; r < 4; r++)
        O[(size_t)(rowb + r) * N + col] = (_Float16)(acc[i][j][r] + bv);
    }
  }
}

__global__ __launch_bounds__(256) void k_gemm_f32(
    const _Float16* __restrict__ A, const _Float16* __restrict__ Bt,
    const float* __restrict__ bias, float* __restrict__ O, int M, int N,
    int K) {
  __shared__ _Float16 sA[128 * 32], sB[128 * 32];
  int t = threadIdx.x, lane = t & 63, wave = t >> 6;
  int wr = wave >> 1, wc = wave & 1;
  int row0 = blockIdx.y * 128, col0 = blockIdx.x * 128;
  floatx4 acc[4][4];
  for (int i = 0; i < 4; i++)
    for (int j = 0; j < 4; j++) acc[i][j] = (floatx4){0.f, 0.f, 0.f, 0.f};
  int rr0 = t >> 2, kk0 = (t & 3) * 8;
  int ar = (lane & 15) * 32 + (lane >> 4) * 8;
  for (int k0 = 0; k0 < K; k0 += 32) {
    __syncthreads();
    async16(&sA[t * 8], &A[(size_t)(row0 + rr0) * K + k0 + kk0]);
    async16(&sA[(t + 256) * 8], &A[(size_t)(row0 + rr0 + 64) * K + k0 + kk0]);
    async16(&sB[t * 8], &Bt[(size_t)(col0 + rr0) * K + k0 + kk0]);
    async16(&sB[(t + 256) * 8], &Bt[(size_t)(col0 + rr0 + 64) * K + k0 + kk0]);
    __syncthreads();
    half8 a[4], b[4];
#pragma unroll
    for (int i = 0; i < 4; i++) {
      a[i] = *(const half8*)&sA[(wr * 64 + i * 16) * 32 + ar];
      b[i] = *(const half8*)&sB[(wc * 64 + i * 16) * 32 + ar];
    }
#pragma unroll
    for (int i = 0; i < 4; i++)
#pragma unroll
      for (int j = 0; j < 4; j++) acc[i][j] = mfma_f16(a[i], b[j], acc[i][j]);
  }
#pragma unroll
  for (int i = 0; i < 4; i++) {
    int rowb = row0 + wr * 64 + i * 16 + ((lane >> 4) << 2);
#pragma unroll
    for (int j = 0; j < 4; j++) {
      int col = col0 + wc * 64 + j * 16 + (lane & 15);
      float bv = bias ? bias[col] : 0.0f;
#pragma unroll
      for (int r = 0; r < 4; r++)
        O[(size_t)(rowb + r) * N + col] = acc[i][j][r] + bv;
    }
  }
}

// ---------------- router (all 4 cycles in one dispatch) ----------------

__global__ __launch_bounds__(256) void k_router4(
    const float* __restrict__ PQ, const float* __restrict__ br1,
    const float* __restrict__ Wr2, const float* __restrict__ br2,
    float* __restrict__ probs, int B) {
  int lane = threadIdx.x & 63;
  int wave = threadIdx.x >> 6;
  int row = blockIdx.x * 4 + wave;
  float cval = (float)blockIdx.y;
  float4 p4 = ((const float4*)(PQ + (size_t)row * 512))[lane];
  float4 q4 = ((const float4*)(PQ + (size_t)row * 512 + 256))[lane];
  float4 b4 = ((const float4*)br1)[lane];
  float rv[4];
  rv[0] = fmaxf(cval * p4.x + q4.x + b4.x, 0.f);
  rv[1] = fmaxf(cval * p4.y + q4.y + b4.y, 0.f);
  rv[2] = fmaxf(cval * p4.z + q4.z + b4.z, 0.f);
  rv[3] = fmaxf(cval * p4.w + q4.w + b4.w, 0.f);
  float lg[8] = {0.f, 0.f, 0.f, 0.f, 0.f, 0.f, 0.f, 0.f};
#pragma unroll
  for (int k = 0; k < 4; k++) {
    const float4* w = (const float4*)(Wr2 + (size_t)(lane * 4 + k) * 8);
    float4 w0 = w[0], w1 = w[1];
    lg[0] += rv[k] * w0.x;
    lg[1] += rv[k] * w0.y;
    lg[2] += rv[k] * w0.z;
    lg[3] += rv[k] * w0.w;
    lg[4] += rv[k] * w1.x;
    lg[5] += rv[k] * w1.y;
    lg[6] += rv[k] * w1.z;
    lg[7] += rv[k] * w1.w;
  }
#pragma unroll
  for (int s = 32; s > 0; s >>= 1)
#pragma unroll
    for (int m = 0; m < 8; m++) lg[m] += __shfl_xor(lg[m], s);
#pragma unroll
  for (int m = 0; m < 8; m++) lg[m] += br2[m];
  float mx = lg[0];
#pragma unroll
  for (int m = 1; m < 8; m++) mx = fmaxf(mx, lg[m]);
  float e[8];
  float sum = 0.f;
#pragma unroll
  for (int m = 0; m < 8; m++) {
    e[m] = expf(lg[m] - mx);
    sum += e[m];
  }
  float inv = 1.f / sum;
  if (lane < 8)
    probs[(size_t)blockIdx.y * B * 8 + (size_t)row * 8 + lane] = e[lane] * inv;
}

// ---------------- expert kernels ----------------

// 512 threads (8 waves), tile 256 rows x 128 cols x 2 experts (z, z+4).
// Wave grid 4x2: each wave computes 64 rows x 64 cols for BOTH experts and
// writes the prob-weighted relu pair-sum to slab[z]. Staged A shared by both
// experts: per-iter staging = 16 KB A + 16 KB B for 256 MFMA (2x R4
// intensity). Partial slabs: 4 (pairs summed in registers).
__global__ __launch_bounds__(512, 2) void k_expert_pair(
    const _Float16* __restrict__ hin, const _Float16* __restrict__ WT,
    const float* __restrict__ bmod, const float* __restrict__ probs,
    _Float16* __restrict__ part, int rowbase) {
  __shared__ _Float16 sA[256 * 32];
  __shared__ _Float16 sB[2 * 128 * 32];
  __shared__ float sProb[2 * 256];
  __shared__ float sBias[2 * 128];
  const int K = 1024;
  int t = threadIdx.x, lane = t & 63, wave = t >> 6;
  int wr = wave >> 1;  // 0..3 row groups (64 rows each)
  int wc = wave & 1;   // 0..1 col groups (64 cols each)
  int z = blockIdx.z;  // experts z and z+4
  int col0 = blockIdx.x * 128;
  int prow0 = blockIdx.y * 256;
  int grow0 = rowbase + prow0;
  // prob/bias staging
  if (t < 512) {
    int e = t >> 8, r = t & 255;
    sProb[t] = probs[(size_t)(grow0 + r) * 8 + z + e * 4];
  }
  if (t < 256) {
    int e = t >> 7, cc = t & 127;
    sBias[t] = bmod[(size_t)(z + e * 4) * 1024 + col0 + cc];
  }
  const _Float16* B0 = WT + (size_t)z * 1024 * 1024;
  const _Float16* B1 = WT + (size_t)(z + 4) * 1024 * 1024;
  floatx4 acc0[4][4], acc1[4][4];
#pragma unroll
  for (int i = 0; i < 4; i++)
#pragma unroll
    for (int j = 0; j < 4; j++) {
      acc0[i][j] = (floatx4){0.f, 0.f, 0.f, 0.f};
      acc1[i][j] = (floatx4){0.f, 0.f, 0.f, 0.f};
    }
  int rr0 = t >> 2, kk0 = (t & 3) * 8;  // A staging: 512 units/round
  int ar = (lane & 15) * 32 + (lane >> 4) * 8;
  for (int k0 = 0; k0 < K; k0 += 32) {
    __syncthreads();
    // A: 256 rows x 32 k = 1024 units of 16B; 2 rounds of 512 threads
    async16(&sA[t * 8], &hin[(size_t)(grow0 + rr0) * K + k0 + kk0]);
    async16(&sA[(t + 512) * 8],
            &hin[(size_t)(grow0 + rr0 + 128) * K + k0 + kk0]);
    // B: 2 experts x 128 rows x 32 k = 512 units each -> 1 round each
    async16(&sB[t * 8], &B0[(size_t)(col0 + rr0) * K + k0 + kk0]);
    async16(&sB[(t + 512) * 8], &B1[(size_t)(col0 + rr0) * K + k0 + kk0]);
    __syncthreads();
    half8 a[4], b0[4], b1[4];
#pragma unroll
    for (int i = 0; i < 4; i++) {
      a[i] = *(const half8*)&sA[(wr * 64 + i * 16) * 32 + ar];
      b0[i] = *(const half8*)&sB[(wc * 64 + i * 16) * 32 + ar];
      b1[i] = *(const half8*)&sB[4096 + (wc * 64 + i * 16) * 32 + ar];
    }
#pragma unroll
    for (int i = 0; i < 4; i++)
#pragma unroll
      for (int j = 0; j < 4; j++) {
        acc0[i][j] = mfma_f16(a[i], b0[j], acc0[i][j]);
        acc1[i][j] = mfma_f16(a[i], b1[j], acc1[i][j]);
      }
  }
#pragma unroll
  for (int i = 0; i < 4; i++) {
    int lr0 = wr * 64 + i * 16 + ((lane >> 4) << 2);  // row in 256-tile
    float p0[4], p1[4];
#pragma unroll
    for (int r = 0; r < 4; r++) {
      p0[r] = sProb[lr0 + r];
      p1[r] = sProb[256 + lr0 + r];
    }
#pragma unroll
    for (int j = 0; j < 4; j++) {
      int cl = wc * 64 + j * 16 + (lane & 15);
      float bb0 = sBias[cl];
      float bb1 = sBias[128 + cl];
      size_t base =
          (size_t)z * CHUNK * 1024 + (size_t)(prow0 + lr0) * 1024 + col0 + cl;
#pragma unroll
      for (int r = 0; r < 4; r++) {
        float v = p0[r] * fmaxf(acc0[i][j][r] + bb0, 0.f) +
                  p1[r] * fmaxf(acc1[i][j][r] + bb1, 0.f);
        part[base + (size_t)r * 1024] = (_Float16)v;
      }
    }
  }
}

// sum 4 pair-slabs (fp16) -> hout rows [rowbase, rowbase+CHUNK)
__global__ __launch_bounds__(256) void k_combine4(
    const _Float16* __restrict__ part, _Float16* __restrict__ hout,
    int rowbase) {
  const size_t S = (size_t)CHUNK * 1024;
  size_t i = ((size_t)blockIdx.x * 256 + threadIdx.x) * 8;
  float s[8] = {0.f, 0.f, 0.f, 0.f, 0.f, 0.f, 0.f, 0.f};
#pragma unroll
  for (int m = 0; m < 4; m++) {
    half8 v = *(const half8*)&part[(size_t)m * S + i];
#pragma unroll
    for (int k = 0; k < 8; k++) s[k] += (float)v[k];
  }
  half8 o;
#pragma unroll
  for (int k = 0; k < 8; k++) o[k] = (_Float16)s[k];
  *(half8*)&hout[(size_t)rowbase * 1024 + i] = o;
}

// ---------------- launcher ----------------

extern "C" void kernel_launch(void* const* d_in, const int* in_sizes, int n_in,
                              void* d_out, int out_size, void* d_ws,
                              size_t ws_size, hipStream_t stream) {
  (void)in_sizes;
  (void)n_in;
  (void)out_size;
  (void)ws_size;
  const float* x = (const float*)d_in[0];
  const float* W_in = (const float*)d_in[1];
  const float* b_in = (const float*)d_in[2];
  const float* W_mod = (const float*)d_in[3];
  const float* b_mod = (const float*)d_in[4];
  const float* Wr1 = (const float*)d_in[5];
  const float* br1 = (const float*)d_in[6];
  const float* Wr2 = (const float*)d_in[7];
  const float* br2 = (const float*)d_in[8];
  const float* Wc = (const float*)d_in[9];
  const float* bc = (const float*)d_in[10];
  const float* W_out = (const float*)d_in[11];
  const float* b_out = (const float*)d_in[12];
  float* out = (float*)d_out;

  const int B = 16384, IN = 512, H = 1024, OUT = 512, M = 8, R = 256;
  const size_t MB = 1024 * 1024;

  char* p = (char*)d_ws;
  // partial (64 MB = 4 slabs x 8192 x 1024 fp16, cycles only) aliases xh
  _Float16* partial = (_Float16*)(p + 0);       // 64 MB
  _Float16* xh = (_Float16*)(p + 0);            // 16 MB (dead after G1)
  _Float16* WinT = (_Float16*)(p + 64 * MB);    // 1 MB  [H][IN]
  _Float16* W1T = (_Float16*)(p + 65 * MB);     // 1 MB  [2R][H]
  _Float16* WoutT = (_Float16*)(p + 66 * MB);   // 1 MB  [OUT][H]
  _Float16* WmodT = (_Float16*)(p + 67 * MB);   // 16 MB [M][H][H]
  _Float16* origHi = (_Float16*)(p + 83 * MB);  // 32 MB [B][H]
  _Float16* hA = (_Float16*)(p + 115 * MB);     // 32 MB
  _Float16* hB = (_Float16*)(p + 147 * MB);     // 32 MB
  float* PQ = (float*)(p + 179 * MB);           // 32 MB [B][512]
  float* probs4 = (float*)(p + 211 * MB);       // 2 MB  [4][B][8]

  // prep
  k_cast16<<<dim3(B * IN / 4 / 256), dim3(256), 0, stream>>>(x, xh,
                                                             B * IN / 4);
  k_transpose16<<<dim3(H / 64, IN / 64, 1), dim3(256), 0, stream>>>(
      W_in, nullptr, WinT, IN, H);
  k_transpose16<<<dim3(R / 64, H / 64, 1), dim3(256), 0, stream>>>(
      Wr1, Wc, W1T, H, R);
  k_transpose16<<<dim3(R / 64, H / 64, 1), dim3(256), 0, stream>>>(
      Wr1, bc, W1T + (size_t)R * H, H, R);
  k_transpose16<<<dim3(OUT / 64, H / 64, 1), dim3(256), 0, stream>>>(
      W_out, nullptr, WoutT, H, OUT);
  k_transpose16<<<dim3(H / 64, H / 64, M), dim3(256), 0, stream>>>(
      W_mod, nullptr, WmodT, H, H);

  // G1: orig = x@W_in + b_in
  k_gemm_f16<<<dim3(H / 128, B / 128), dim3(256), 0, stream>>>(
      xh, WinT, b_in, origHi, B, H, IN);
  // G2: PQ = orig@[diag(Wc)Wr1 | diag(bc)Wr1]
  k_gemm_f32<<<dim3(2 * R / 128, B / 128), dim3(256), 0, stream>>>(
      origHi, W1T, nullptr, PQ, B, 2 * R, H);
  // router: all 4 cycles' probs
  k_router4<<<dim3(B / 4, 4), dim3(256), 0, stream>>>(PQ, br1, Wr2, br2,
                                                      probs4, B);

  // 4 cycles, 2 row-chunks of 8192
  const _Float16* hcur = origHi;
  _Float16* hbufs[2] = {hA, hB};
  for (int c = 0; c < 4; c++) {
    const float* probs = probs4 + (size_t)c * B * 8;
    _Float16* hn = hbufs[c & 1];
    for (int chunk = 0; chunk < 2; chunk++) {
      int rowbase = chunk * CHUNK;
      k_expert_pair<<<dim3(H / 128, CHUNK / 256, 4), dim3(512), 0, stream>>>(
          hcur, WmodT, b_mod, probs, partial, rowbase);
      k_combine4<<<dim3(CHUNK * 1024 / (256 * 8)), dim3(256), 0, stream>>>(
          partial, hn, rowbase);
    }
    hcur = hn;
  }

  // G3: out = h@W_out + b_out
  k_gemm_f32<<<dim3(OUT / 128, B / 128), dim3(256), 0, stream>>>(
      hcur, WoutT, b_out, out, B, OUT, H);
}

// Round 6
// 1752.274 us; speedup vs baseline: 1.2547x; 1.0031x over previous
//
#include <hip/hip_runtime.h>

// Router_15942918603252 — MI355X implementation (R6).
// R6: double-buffered global_load_lds in k_expert_pair. R5 post-mortem:
// expert GEMM stalls ~1100 cyc/iter on the barrier vmcnt(0) drain (loads
// issued after the barrier, consumed immediately; 2 blocks/CU can't hide
// ~900 cyc latency). Now loads for tile k+1 are issued right after the
// barrier into the other LDS buffer, aging a full MFMA phase (~2500 cyc)
// before they're needed -> drain ~free. LDS 67 KB, still 2 blocks/CU.
//
// Pipeline: prep (fp16 cast/transposes) -> G1 orig = x@W_in+b_in ->
// G2 PQ = orig@[diag(Wc)Wr1 | diag(bc)Wr1] -> router4 (all 4 cycles) ->
// 4x { 2 row-chunks x (k_expert_pair; k_combine4) } -> G3 out.
// max_cycles==4 hardcoded (setup_inputs constant).

typedef _Float16 half8 __attribute__((ext_vector_type(8)));
typedef _Float16 half4v __attribute__((ext_vector_type(4)));
typedef float floatx4 __attribute__((ext_vector_type(4)));

#define DEVI __device__ __forceinline__
#define CHUNK 8192

DEVI void async16(void* lds, const void* g) {
  __builtin_amdgcn_global_load_lds(
      (const __attribute__((address_space(1))) unsigned int*)g,
      (__attribute__((address_space(3))) unsigned int*)lds, 16, 0, 0);
}

DEVI floatx4 mfma_f16(half8 a, half8 b, floatx4 c) {
  return __builtin_amdgcn_mfma_f32_16x16x32_f16(a, b, c, 0, 0, 0);
}

// ---------------- prep kernels ----------------

__global__ __launch_bounds__(256) void k_cast16(const float* __restrict__ in,
                                                _Float16* __restrict__ o,
                                                int n4) {
  int i = blockIdx.x * 256 + threadIdx.x;
  if (i >= n4) return;
  float4 v = ((const float4*)in)[i];
  half4v h;
  h[0] = (_Float16)v.x;
  h[1] = (_Float16)v.y;
  h[2] = (_Float16)v.z;
  h[3] = (_Float16)v.w;
  ((half4v*)o)[i] = h;
}

// in: [batch][R][C] f32; optional per-input-row scale[r]. out: [batch][C][R]
__global__ __launch_bounds__(256) void k_transpose16(
    const float* __restrict__ in, const float* __restrict__ scale,
    _Float16* __restrict__ o, int R, int C) {
  __shared__ float tile[64][65];
  __shared__ float srow[64];
  int b = blockIdx.z;
  int r0 = blockIdx.y * 64, c0 = blockIdx.x * 64;
  const float* src = in + (size_t)b * R * C;
  int t = threadIdx.x;
  int lr = t >> 4;
  int lc4 = (t & 15) * 4;
#pragma unroll
  for (int rr = 0; rr < 64; rr += 16) {
    float4 v = *(const float4*)&src[(size_t)(r0 + lr + rr) * C + c0 + lc4];
    tile[lr + rr][lc4 + 0] = v.x;
    tile[lr + rr][lc4 + 1] = v.y;
    tile[lr + rr][lc4 + 2] = v.z;
    tile[lr + rr][lc4 + 3] = v.w;
  }
  if (t < 64) srow[t] = scale ? scale[r0 + t] : 1.0f;
  __syncthreads();
  int oc = t >> 2;
  int orr = (t & 3) * 16;
  alignas(16) _Float16 hv[16];
#pragma unroll
  for (int k = 0; k < 16; k++)
    hv[k] = (_Float16)(tile[orr + k][oc] * srow[orr + k]);
  size_t ob = (size_t)b * C * R + (size_t)(c0 + oc) * R + (r0 + orr);
  ((int4*)&o[ob])[0] = ((int4*)hv)[0];
  ((int4*)&o[ob])[1] = ((int4*)hv)[1];
}

// ---------------- generic GEMMs (m97 structure, 128x128, 4 waves) ----------

__global__ __launch_bounds__(256) void k_gemm_f16(
    const _Float16* __restrict__ A, const _Float16* __restrict__ Bt,
    const float* __restrict__ bias, _Float16* __restrict__ O, int M, int N,
    int K) {
  __shared__ _Float16 sA[128 * 32], sB[128 * 32];
  int t = threadIdx.x, lane = t & 63, wave = t >> 6;
  int wr = wave >> 1, wc = wave & 1;
  int row0 = blockIdx.y * 128, col0 = blockIdx.x * 128;
  floatx4 acc[4][4];
  for (int i = 0; i < 4; i++)
    for (int j = 0; j < 4; j++) acc[i][j] = (floatx4){0.f, 0.f, 0.f, 0.f};
  int rr0 = t >> 2, kk0 = (t & 3) * 8;
  int ar = (lane & 15) * 32 + (lane >> 4) * 8;
  for (int k0 = 0; k0 < K; k0 += 32) {
    __syncthreads();
    async16(&sA[t * 8], &A[(size_t)(row0 + rr0) * K + k0 + kk0]);
    async16(&sA[(t + 256) * 8], &A[(size_t)(row0 + rr0 + 64) * K + k0 + kk0]);
    async16(&sB[t * 8], &Bt[(size_t)(col0 + rr0) * K + k0 + kk0]);
    async16(&sB[(t + 256) * 8], &Bt[(size_t)(col0 + rr0 + 64) * K + k0 + kk0]);
    __syncthreads();
    half8 a[4], b[4];
#pragma unroll
    for (int i = 0; i < 4; i++) {
      a[i] = *(const half8*)&sA[(wr * 64 + i * 16) * 32 + ar];
      b[i] = *(const half8*)&sB[(wc * 64 + i * 16) * 32 + ar];
    }
#pragma unroll
    for (int i = 0; i < 4; i++)
#pragma unroll
      for (int j = 0; j < 4; j++) acc[i][j] = mfma_f16(a[i], b[j], acc[i][j]);
  }
#pragma unroll
  for (int i = 0; i < 4; i++) {
    int rowb = row0 + wr * 64 + i * 16 + ((lane >> 4) << 2);
#pragma unroll
    for (int j = 0; j < 4; j++) {
      int col = col0 + wc * 64 + j * 16 + (lane & 15);
      float bv = bias ? bias[col] : 0.0f;
#pragma unroll
      for (int r = 0; r < 4; r++)
        O[(size_t)(rowb + r) * N + col] = (_Float16)(acc[i][j][r] + bv);
    }
  }
}

__global__ __launch_bounds__(256) void k_gemm_f32(
    const _Float16* __restrict__ A, const _Float16* __restrict__ Bt,
    const float* __restrict__ bias, float* __restrict__ O, int M, int N,
    int K) {
  __shared__ _Float16 sA[128 * 32], sB[128 * 32];
  int t = threadIdx.x, lane = t & 63, wave = t >> 6;
  int wr = wave >> 1, wc = wave & 1;
  int row0 = blockIdx.y * 128, col0 = blockIdx.x * 128;
  floatx4 acc[4][4];
  for (int i = 0; i < 4; i++)
    for (int j = 0; j < 4; j++) acc[i][j] = (floatx4){0.f, 0.f, 0.f, 0.f};
  int rr0 = t >> 2, kk0 = (t & 3) * 8;
  int ar = (lane & 15) * 32 + (lane >> 4) * 8;
  for (int k0 = 0; k0 < K; k0 += 32) {
    __syncthreads();
    async16(&sA[t * 8], &A[(size_t)(row0 + rr0) * K + k0 + kk0]);
    async16(&sA[(t + 256) * 8], &A[(size_t)(row0 + rr0 + 64) * K + k0 + kk0]);
    async16(&sB[t * 8], &Bt[(size_t)(col0 + rr0) * K + k0 + kk0]);
    async16(&sB[(t + 256) * 8], &Bt[(size_t)(col0 + rr0 + 64) * K + k0 + kk0]);
    __syncthreads();
    half8 a[4], b[4];
#pragma unroll
    for (int i = 0; i < 4; i++) {
      a[i] = *(const half8*)&sA[(wr * 64 + i * 16) * 32 + ar];
      b[i] = *(const half8*)&sB[(wc * 64 + i * 16) * 32 + ar];
    }
#pragma unroll
    for (int i = 0; i < 4; i++)
#pragma unroll
      for (int j = 0; j < 4; j++) acc[i][j] = mfma_f16(a[i], b[j], acc[i][j]);
  }
#pragma unroll
  for (int i = 0; i < 4; i++) {
    int rowb = row0 + wr * 64 + i * 16 + ((lane >> 4) << 2);
#pragma unroll
    for (int j = 0; j < 4; j++) {
      int col = col0 + wc * 64 + j * 16 + (lane & 15);
      float bv = bias ? bias[col] : 0.0f;
#pragma unroll
      for (int r = 0; r < 4; r++)
        O[(size_t)(rowb + r) * N + col] = acc[i][j][r] + bv;
    }
  }
}

// ---------------- router (all 4 cycles in one dispatch) ----------------

__global__ __launch_bounds__(256) void k_router4(
    const float* __restrict__ PQ, const float* __restrict__ br1,
    const float* __restrict__ Wr2, const float* __restrict__ br2,
    float* __restrict__ probs, int B) {
  int lane = threadIdx.x & 63;
  int wave = threadIdx.x >> 6;
  int row = blockIdx.x * 4 + wave;
  float cval = (float)blockIdx.y;
  float4 p4 = ((const float4*)(PQ + (size_t)row * 512))[lane];
  float4 q4 = ((const float4*)(PQ + (size_t)row * 512 + 256))[lane];
  float4 b4 = ((const float4*)br1)[lane];
  float rv[4];
  rv[0] = fmaxf(cval * p4.x + q4.x + b4.x, 0.f);
  rv[1] = fmaxf(cval * p4.y + q4.y + b4.y, 0.f);
  rv[2] = fmaxf(cval * p4.z + q4.z + b4.z, 0.f);
  rv[3] = fmaxf(cval * p4.w + q4.w + b4.w, 0.f);
  float lg[8] = {0.f, 0.f, 0.f, 0.f, 0.f, 0.f, 0.f, 0.f};
#pragma unroll
  for (int k = 0; k < 4; k++) {
    const float4* w = (const float4*)(Wr2 + (size_t)(lane * 4 + k) * 8);
    float4 w0 = w[0], w1 = w[1];
    lg[0] += rv[k] * w0.x;
    lg[1] += rv[k] * w0.y;
    lg[2] += rv[k] * w0.z;
    lg[3] += rv[k] * w0.w;
    lg[4] += rv[k] * w1.x;
    lg[5] += rv[k] * w1.y;
    lg[6] += rv[k] * w1.z;
    lg[7] += rv[k] * w1.w;
  }
#pragma unroll
  for (int s = 32; s > 0; s >>= 1)
#pragma unroll
    for (int m = 0; m < 8; m++) lg[m] += __shfl_xor(lg[m], s);
#pragma unroll
  for (int m = 0; m < 8; m++) lg[m] += br2[m];
  float mx = lg[0];
#pragma unroll
  for (int m = 1; m < 8; m++) mx = fmaxf(mx, lg[m]);
  float e[8];
  float sum = 0.f;
#pragma unroll
  for (int m = 0; m < 8; m++) {
    e[m] = expf(lg[m] - mx);
    sum += e[m];
  }
  float inv = 1.f / sum;
  if (lane < 8)
    probs[(size_t)blockIdx.y * B * 8 + (size_t)row * 8 + lane] = e[lane] * inv;
}

// ---------------- expert kernels ----------------

// 512 threads (8 waves), tile 256 rows x 128 cols x 2 experts (z, z+4),
// double-buffered LDS: loads for tile k+1 issued right after the barrier,
// consumed one iteration later (prefetch ages a full MFMA phase).
__global__ __launch_bounds__(512, 2) void k_expert_pair(
    const _Float16* __restrict__ hin, const _Float16* __restrict__ WT,
    const float* __restrict__ bmod, const float* __restrict__ probs,
    _Float16* __restrict__ part, int rowbase) {
  __shared__ _Float16 sA[2][256 * 32];
  __shared__ _Float16 sB[2][2 * 128 * 32];
  __shared__ float sProb[2 * 256];
  __shared__ float sBias[2 * 128];
  const int K = 1024;
  int t = threadIdx.x, lane = t & 63, wave = t >> 6;
  int wr = wave >> 1;  // 0..3 row groups (64 rows each)
  int wc = wave & 1;   // 0..1 col groups (64 cols each)
  int z = blockIdx.z;  // experts z and z+4
  int col0 = blockIdx.x * 128;
  int prow0 = blockIdx.y * 256;
  int grow0 = rowbase + prow0;
  {
    int e = t >> 8, r = t & 255;
    sProb[t] = probs[(size_t)(grow0 + r) * 8 + z + e * 4];
  }
  if (t < 256) {
    int e = t >> 7, cc = t & 127;
    sBias[t] = bmod[(size_t)(z + e * 4) * 1024 + col0 + cc];
  }
  const _Float16* B0 = WT + (size_t)z * 1024 * 1024;
  const _Float16* B1 = WT + (size_t)(z + 4) * 1024 * 1024;
  floatx4 acc0[4][4], acc1[4][4];
#pragma unroll
  for (int i = 0; i < 4; i++)
#pragma unroll
    for (int j = 0; j < 4; j++) {
      acc0[i][j] = (floatx4){0.f, 0.f, 0.f, 0.f};
      acc1[i][j] = (floatx4){0.f, 0.f, 0.f, 0.f};
    }
  int rr0 = t >> 2, kk0 = (t & 3) * 8;
  int ar = (lane & 15) * 32 + (lane >> 4) * 8;
  const size_t aoff0 = (size_t)(grow0 + rr0) * K + kk0;
  const size_t aoff1 = (size_t)(grow0 + rr0 + 128) * K + kk0;
  const size_t boff = (size_t)(col0 + rr0) * K + kk0;
  // prologue: stage k=0 into buffer 0
  async16(&sA[0][t * 8], &hin[aoff0]);
  async16(&sA[0][(t + 512) * 8], &hin[aoff1]);
  async16(&sB[0][t * 8], &B0[boff]);
  async16(&sB[0][(t + 512) * 8], &B1[boff]);
  for (int k0 = 0; k0 < K; k0 += 32) {
    int cur = (k0 >> 5) & 1;
    __syncthreads();  // drains buf[cur] loads (issued one iter ago) + guards
                      // buf[1-cur] against still-reading waves
    if (k0 + 32 < K) {
      int nxt = 1 - cur;
      async16(&sA[nxt][t * 8], &hin[aoff0 + k0 + 32]);
      async16(&sA[nxt][(t + 512) * 8], &hin[aoff1 + k0 + 32]);
      async16(&sB[nxt][t * 8], &B0[boff + k0 + 32]);
      async16(&sB[nxt][(t + 512) * 8], &B1[boff + k0 + 32]);
    }
    half8 a[4], b0[4], b1[4];
#pragma unroll
    for (int i = 0; i < 4; i++) {
      a[i] = *(const half8*)&sA[cur][(wr * 64 + i * 16) * 32 + ar];
      b0[i] = *(const half8*)&sB[cur][(wc * 64 + i * 16) * 32 + ar];
      b1[i] = *(const half8*)&sB[cur][4096 + (wc * 64 + i * 16) * 32 + ar];
    }
#pragma unroll
    for (int i = 0; i < 4; i++)
#pragma unroll
      for (int j = 0; j < 4; j++) {
        acc0[i][j] = mfma_f16(a[i], b0[j], acc0[i][j]);
        acc1[i][j] = mfma_f16(a[i], b1[j], acc1[i][j]);
      }
  }
#pragma unroll
  for (int i = 0; i < 4; i++) {
    int lr0 = wr * 64 + i * 16 + ((lane >> 4) << 2);  // row in 256-tile
    float p0[4], p1[4];
#pragma unroll
    for (int r = 0; r < 4; r++) {
      p0[r] = sProb[lr0 + r];
      p1[r] = sProb[256 + lr0 + r];
    }
#pragma unroll
    for (int j = 0; j < 4; j++) {
      int cl = wc * 64 + j * 16 + (lane & 15);
      float bb0 = sBias[cl];
      float bb1 = sBias[128 + cl];
      size_t base =
          (size_t)z * CHUNK * 1024 + (size_t)(prow0 + lr0) * 1024 + col0 + cl;
#pragma unroll
      for (int r = 0; r < 4; r++) {
        float v = p0[r] * fmaxf(acc0[i][j][r] + bb0, 0.f) +
                  p1[r] * fmaxf(acc1[i][j][r] + bb1, 0.f);
        part[base + (size_t)r * 1024] = (_Float16)v;
      }
    }
  }
}

// sum 4 pair-slabs (fp16) -> hout rows [rowbase, rowbase+CHUNK)
__global__ __launch_bounds__(256) void k_combine4(
    const _Float16* __restrict__ part, _Float16* __restrict__ hout,
    int rowbase) {
  const size_t S = (size_t)CHUNK * 1024;
  size_t i = ((size_t)blockIdx.x * 256 + threadIdx.x) * 8;
  float s[8] = {0.f, 0.f, 0.f, 0.f, 0.f, 0.f, 0.f, 0.f};
#pragma unroll
  for (int m = 0; m < 4; m++) {
    half8 v = *(const half8*)&part[(size_t)m * S + i];
#pragma unroll
    for (int k = 0; k < 8; k++) s[k] += (float)v[k];
  }
  half8 o;
#pragma unroll
  for (int k = 0; k < 8; k++) o[k] = (_Float16)s[k];
  *(half8*)&hout[(size_t)rowbase * 1024 + i] = o;
}

// ---------------- launcher ----------------

extern "C" void kernel_launch(void* const* d_in, const int* in_sizes, int n_in,
                              void* d_out, int out_size, void* d_ws,
                              size_t ws_size, hipStream_t stream) {
  (void)in_sizes;
  (void)n_in;
  (void)out_size;
  (void)ws_size;
  const float* x = (const float*)d_in[0];
  const float* W_in = (const float*)d_in[1];
  const float* b_in = (const float*)d_in[2];
  const float* W_mod = (const float*)d_in[3];
  const float* b_mod = (const float*)d_in[4];
  const float* Wr1 = (const float*)d_in[5];
  const float* br1 = (const float*)d_in[6];
  const float* Wr2 = (const float*)d_in[7];
  const float* br2 = (const float*)d_in[8];
  const float* Wc = (const float*)d_in[9];
  const float* bc = (const float*)d_in[10];
  const float* W_out = (const float*)d_in[11];
  const float* b_out = (const float*)d_in[12];
  float* out = (float*)d_out;

  const int B = 16384, IN = 512, H = 1024, OUT = 512, M = 8, R = 256;
  const size_t MB = 1024 * 1024;

  char* p = (char*)d_ws;
  // partial (64 MB = 4 slabs x 8192 x 1024 fp16, cycles only) aliases xh
  _Float16* partial = (_Float16*)(p + 0);       // 64 MB
  _Float16* xh = (_Float16*)(p + 0);            // 16 MB (dead after G1)
  _Float16* WinT = (_Float16*)(p + 64 * MB);    // 1 MB  [H][IN]
  _Float16* W1T = (_Float16*)(p + 65 * MB);     // 1 MB  [2R][H]
  _Float16* WoutT = (_Float16*)(p + 66 * MB);   // 1 MB  [OUT][H]
  _Float16* WmodT = (_Float16*)(p + 67 * MB);   // 16 MB [M][H][H]
  _Float16* origHi = (_Float16*)(p + 83 * MB);  // 32 MB [B][H]
  _Float16* hA = (_Float16*)(p + 115 * MB);     // 32 MB
  _Float16* hB = (_Float16*)(p + 147 * MB);     // 32 MB
  float* PQ = (float*)(p + 179 * MB);           // 32 MB [B][512]
  float* probs4 = (float*)(p + 211 * MB);       // 2 MB  [4][B][8]

  // prep
  k_cast16<<<dim3(B * IN / 4 / 256), dim3(256), 0, stream>>>(x, xh,
                                                             B * IN / 4);
  k_transpose16<<<dim3(H / 64, IN / 64, 1), dim3(256), 0, stream>>>(
      W_in, nullptr, WinT, IN, H);
  k_transpose16<<<dim3(R / 64, H / 64, 1), dim3(256), 0, stream>>>(
      Wr1, Wc, W1T, H, R);
  k_transpose16<<<dim3(R / 64, H / 64, 1), dim3(256), 0, stream>>>(
      Wr1, bc, W1T + (size_t)R * H, H, R);
  k_transpose16<<<dim3(OUT / 64, H / 64, 1), dim3(256), 0, stream>>>(
      W_out, nullptr, WoutT, H, OUT);
  k_transpose16<<<dim3(H / 64, H / 64, M), dim3(256), 0, stream>>>(
      W_mod, nullptr, WmodT, H, H);

  // G1: orig = x@W_in + b_in
  k_gemm_f16<<<dim3(H / 128, B / 128), dim3(256), 0, stream>>>(
      xh, WinT, b_in, origHi, B, H, IN);
  // G2: PQ = orig@[diag(Wc)Wr1 | diag(bc)Wr1]
  k_gemm_f32<<<dim3(2 * R / 128, B / 128), dim3(256), 0, stream>>>(
      origHi, W1T, nullptr, PQ, B, 2 * R, H);
  // router: all 4 cycles' probs
  k_router4<<<dim3(B / 4, 4), dim3(256), 0, stream>>>(PQ, br1, Wr2, br2,
                                                      probs4, B);

  // 4 cycles, 2 row-chunks of 8192
  const _Float16* hcur = origHi;
  _Float16* hbufs[2] = {hA, hB};
  for (int c = 0; c < 4; c++) {
    const float* probs = probs4 + (size_t)c * B * 8;
    _Float16* hn = hbufs[c & 1];
    for (int chunk = 0; chunk < 2; chunk++) {
      int rowbase = chunk * CHUNK;
      k_expert_pair<<<dim3(H / 128, CHUNK / 256, 4), dim3(512), 0, stream>>>(
          hcur, WmodT, b_mod, probs, partial, rowbase);
      k_combine4<<<dim3(CHUNK * 1024 / (256 * 8)), dim3(256), 0, stream>>>(
          partial, hn, rowbase);
    }
    hcur = hn;
  }

  // G3: out = h@W_out + b_out
  k_gemm_f32<<<dim3(OUT / 128, B / 128), dim3(256), 0, stream>>>(
      hcur, WoutT, b_out, out, B, OUT, H);
}